// Round 1
// baseline (100.595 us; speedup 1.0000x reference)
//
#include <hip/hip_runtime.h>

typedef unsigned short ushort_t;
typedef __bf16 bf16x8 __attribute__((ext_vector_type(8)));
typedef float f32x4 __attribute__((ext_vector_type(4)));
typedef void __attribute__((address_space(1))) gvoid_t;
typedef void __attribute__((address_space(3))) lvoid_t;

__device__ __forceinline__ float bflo(unsigned u) { return __builtin_bit_cast(float, u << 16); }
__device__ __forceinline__ float bfhi(unsigned u) { return __builtin_bit_cast(float, u & 0xffff0000u); }
__device__ __forceinline__ unsigned f2bf_bits(float f) {
  unsigned u = __builtin_bit_cast(unsigned, f);
  return (u + 0x7fffu + ((u >> 16) & 1u)) >> 16;
}
__device__ __forceinline__ ushort_t f2bf(float f) { return (ushort_t)f2bf_bits(f); }

// ---------------- prep: weight (o,c,k) f32 -> wb[k][o][c] bf16 ----------------
__global__ __launch_bounds__(256) void k_prep_w(const float* __restrict__ w,
                                                ushort_t* __restrict__ wb) {
  const int idx = blockIdx.x * 256 + threadIdx.x;  // (o,c) pair, 65536 total
  const float* src = w + (size_t)idx * 9;
  #pragma unroll
  for (int k = 0; k < 9; ++k)
    wb[(k << 16) + idx] = f2bf(src[k]);
}

// ---------------- prep: x (b,c,h,w) f32 -> xt[b][h][w][c] bf16 ----------------
__global__ __launch_bounds__(256) void k_prep_x(const float* __restrict__ x,
                                                ushort_t* __restrict__ xt) {
  __shared__ ushort_t tile[64][68];
  const int bid = blockIdx.x;             // 4b * 4ct * 64pt = 1024
  const int b = bid >> 8;
  const int ct = (bid >> 6) & 3;
  const int pt = bid & 63;
  const int t = threadIdx.x;
  const float* xb = x + ((size_t)(b * 256 + ct * 64)) * 4096 + pt * 64;
  #pragma unroll
  for (int i = 0; i < 16; ++i) {
    const int idx = t + 256 * i;
    const int c_l = idx >> 6, p_l = idx & 63;
    tile[c_l][p_l] = f2bf(xb[(size_t)c_l * 4096 + p_l]);
  }
  __syncthreads();
  ushort_t* xo = xt + ((size_t)(b * 4096 + pt * 64)) * 256 + ct * 64;
  #pragma unroll
  for (int i = 0; i < 16; ++i) {
    const int idx = t + 256 * i;
    const int p_l = idx >> 6, c_l = idx & 63;
    xo[(size_t)p_l * 256 + c_l] = tile[c_l][p_l];
  }
}

// ---------------- fused deform-sample + GEMM ----------------
// block = one output row (b,h): BM=64 (w), BN=256 (o). K-loop: 9 taps x 4 chunks of 64 ch.
__global__ __launch_bounds__(256) void k_gemm(const float* __restrict__ off,
                                              const ushort_t* __restrict__ xt,
                                              const ushort_t* __restrict__ wb,
                                              float* __restrict__ y) {
  __shared__ __attribute__((aligned(16))) ushort_t Abuf[64 * 64];   // [w][64c] swizzled, 8KB
  __shared__ __attribute__((aligned(16))) ushort_t Bbuf[256 * 64];  // [o][64c] swizzled, 32KB

  const int bid = blockIdx.x;  // 256
  const int b = bid >> 6;
  const int h = bid & 63;
  const int t = threadIdx.x;
  const int wave = t >> 6;
  const int lane = t & 63;
  const int wq = lane >> 4;
  const int wr = lane & 15;

  const int s_w = t >> 2;   // sampling: which w column (0..63)
  const int c4i = t & 3;    // sampling: which 8-channel slice

  const f32x4 zero = {0.f, 0.f, 0.f, 0.f};
  f32x4 acc[4][4];
  #pragma unroll
  for (int i = 0; i < 4; ++i)
    #pragma unroll
    for (int j = 0; j < 4; ++j) acc[i][j] = zero;

  const float* offb = off + (size_t)b * 18 * 4096 + h * 64 + s_w;
  const ushort_t* xtb = xt + (size_t)b * 4096 * 256;

  for (int k = 0; k < 9; ++k) {
    // bilinear meta for (s_w, k) — reused over all channels
    const float offy = offb[(2 * k) * 4096];
    const float offx = offb[(2 * k + 1) * 4096];
    const float py = (float)(h - 1 + k / 3) + offy;
    const float px = (float)(s_w - 1 + k % 3) + offx;
    const float fy = floorf(py), fx = floorf(px);
    const float ly = py - fy, lx = px - fx;
    const int iy0 = (int)fy, ix0 = (int)fx;
    const float vy0 = (iy0 >= 0 && iy0 < 64) ? 1.f : 0.f;
    const float vy1 = (iy0 >= -1 && iy0 < 63) ? 1.f : 0.f;
    const float vx0 = (ix0 >= 0 && ix0 < 64) ? 1.f : 0.f;
    const float vx1 = (ix0 >= -1 && ix0 < 63) ? 1.f : 0.f;
    const float w00 = (1.f - ly) * (1.f - lx) * vy0 * vx0;
    const float w01 = (1.f - ly) * lx * vy0 * vx1;
    const float w10 = ly * (1.f - lx) * vy1 * vx0;
    const float w11 = ly * lx * vy1 * vx1;
    const int cy0 = min(max(iy0, 0), 63), cy1 = min(max(iy0 + 1, 0), 63);
    const int cx0 = min(max(ix0, 0), 63), cx1 = min(max(ix0 + 1, 0), 63);
    const ushort_t* p00 = xtb + (cy0 * 64 + cx0) * 256;
    const ushort_t* p01 = xtb + (cy0 * 64 + cx1) * 256;
    const ushort_t* p10 = xtb + (cy1 * 64 + cx0) * 256;
    const ushort_t* p11 = xtb + (cy1 * 64 + cx1) * 256;

    for (int c0 = 0; c0 < 256; c0 += 64) {
      __syncthreads();  // previous chunk's frag reads done before overwrite
      // ---- stage A: sample 2x8 channels, pack bf16, swizzled ds_write_b128 ----
      #pragma unroll
      for (int hf = 0; hf < 2; ++hf) {
        const int cc = c0 + hf * 32 + c4i * 8;
        const uint4 q00 = *(const uint4*)(p00 + cc);
        const uint4 q01 = *(const uint4*)(p01 + cc);
        const uint4 q10 = *(const uint4*)(p10 + cc);
        const uint4 q11 = *(const uint4*)(p11 + cc);
        uint4 r;
        {
          float lo = w00 * bflo(q00.x) + w01 * bflo(q01.x) + w10 * bflo(q10.x) + w11 * bflo(q11.x);
          float hi = w00 * bfhi(q00.x) + w01 * bfhi(q01.x) + w10 * bfhi(q10.x) + w11 * bfhi(q11.x);
          r.x = f2bf_bits(lo) | (f2bf_bits(hi) << 16);
        }
        {
          float lo = w00 * bflo(q00.y) + w01 * bflo(q01.y) + w10 * bflo(q10.y) + w11 * bflo(q11.y);
          float hi = w00 * bfhi(q00.y) + w01 * bfhi(q01.y) + w10 * bfhi(q10.y) + w11 * bfhi(q11.y);
          r.y = f2bf_bits(lo) | (f2bf_bits(hi) << 16);
        }
        {
          float lo = w00 * bflo(q00.z) + w01 * bflo(q01.z) + w10 * bflo(q10.z) + w11 * bflo(q11.z);
          float hi = w00 * bfhi(q00.z) + w01 * bfhi(q01.z) + w10 * bfhi(q10.z) + w11 * bfhi(q11.z);
          r.z = f2bf_bits(lo) | (f2bf_bits(hi) << 16);
        }
        {
          float lo = w00 * bflo(q00.w) + w01 * bflo(q01.w) + w10 * bflo(q10.w) + w11 * bflo(q11.w);
          float hi = w00 * bfhi(q00.w) + w01 * bfhi(q01.w) + w10 * bfhi(q10.w) + w11 * bfhi(q11.w);
          r.w = f2bf_bits(lo) | (f2bf_bits(hi) << 16);
        }
        const int slot = (hf * 4 + c4i) ^ (s_w & 7);
        *(uint4*)&Abuf[s_w * 64 + slot * 8] = r;
      }
      // ---- stage B: global_load_lds w=16, linear LDS dest, pre-swizzled global src ----
      #pragma unroll
      for (int i = 0; i < 8; ++i) {
        const int row = i * 32 + (t >> 3);
        const int slot = t & 7;
        const int cl = ((slot ^ (row & 7)) << 3);
        const ushort_t* g = wb + (((k << 8) + row) << 8) + c0 + cl;
        __builtin_amdgcn_global_load_lds((gvoid_t*)g,
                                         (lvoid_t*)((char*)Bbuf + i * 4096 + t * 16),
                                         16, 0, 0);
      }
      __syncthreads();
      // ---- MFMA: 2 K-steps of 32 ----
      #pragma unroll
      for (int ks = 0; ks < 2; ++ks) {
        bf16x8 af[4], bfr[4];
        #pragma unroll
        for (int tm = 0; tm < 4; ++tm) {
          const int row = tm * 16 + wr;
          const int slot = (ks * 4 + wq) ^ (row & 7);
          af[tm] = *(const bf16x8*)&Abuf[row * 64 + slot * 8];
        }
        #pragma unroll
        for (int tn = 0; tn < 4; ++tn) {
          const int row = wave * 64 + tn * 16 + wr;
          const int slot = (ks * 4 + wq) ^ (row & 7);
          bfr[tn] = *(const bf16x8*)&Bbuf[row * 64 + slot * 8];
        }
        #pragma unroll
        for (int tm = 0; tm < 4; ++tm)
          #pragma unroll
          for (int tn = 0; tn < 4; ++tn)
            acc[tm][tn] =
                __builtin_amdgcn_mfma_f32_16x16x32_bf16(af[tm], bfr[tn], acc[tm][tn], 0, 0, 0);
      }
    }
  }
  // ---- epilogue: y[b][s][o], D layout col=lane&15, row=(lane>>4)*4+r ----
  float* yb = y + ((size_t)(b * 4096 + h * 64)) * 256;
  #pragma unroll
  for (int tm = 0; tm < 4; ++tm) {
    #pragma unroll
    for (int tn = 0; tn < 4; ++tn) {
      const int o = wave * 64 + tn * 16 + wr;
      #pragma unroll
      for (int r2 = 0; r2 < 4; ++r2) {
        const int ww = tm * 16 + wq * 4 + r2;
        yb[ww * 256 + o] = acc[tm][tn][r2];
      }
    }
  }
}

// ---------------- GN stats: sum/sumsq per (b, group) ----------------
__global__ __launch_bounds__(256) void k_stats(const float* __restrict__ y,
                                               float* __restrict__ stats) {
  const int bid = blockIdx.x;  // 32: b(4) x s-chunk(8)
  const int b = bid >> 3, ch = bid & 7;
  const int t = threadIdx.x;  // = o
  float sum = 0.f, ss = 0.f;
  const float* p = y + ((size_t)(b * 4096 + ch * 512)) * 256 + t;
  for (int s = 0; s < 512; ++s) {
    const float v = p[(size_t)s * 256];
    sum += v;
    ss += v * v;
  }
  #pragma unroll
  for (int d = 1; d < 8; d <<= 1) {
    sum += __shfl_xor(sum, d, 64);
    ss += __shfl_xor(ss, d, 64);
  }
  if ((t & 7) == 0) {
    const int g = t >> 3;
    atomicAdd(&stats[(b * 32 + g) * 2], sum);
    atomicAdd(&stats[(b * 32 + g) * 2 + 1], ss);
  }
}

// ---------------- GN apply + ReLU, transpose [b][s][o] -> [b][o][s] ----------------
__global__ __launch_bounds__(256) void k_apply(const float* __restrict__ y,
                                               const float* __restrict__ stats,
                                               const float* __restrict__ gamma,
                                               const float* __restrict__ beta,
                                               float* __restrict__ out) {
  __shared__ float tile[64][65];
  __shared__ float sm[8], sr[8], sg[64], sb[64];
  const int bid = blockIdx.x;  // b(4) x st(64) x ot(4) = 1024
  const int b = bid >> 8;
  const int st = (bid >> 2) & 63;
  const int ot = bid & 3;
  const int t = threadIdx.x;
  if (t < 8) {
    const int g = ot * 8 + t;
    const float s1 = stats[(b * 32 + g) * 2];
    const float s2 = stats[(b * 32 + g) * 2 + 1];
    const float mean = s1 * (1.f / 32768.f);
    const float var = s2 * (1.f / 32768.f) - mean * mean;
    sm[t] = mean;
    sr[t] = rsqrtf(var + 1e-5f);
  }
  if (t < 64) {
    sg[t] = gamma[ot * 64 + t];
    sb[t] = beta[ot * 64 + t];
  }
  const float* yb = y + ((size_t)(b * 4096 + st * 64)) * 256 + ot * 64;
  #pragma unroll
  for (int i = 0; i < 16; ++i) {
    const int idx = t + 256 * i;
    const int s_l = idx >> 6, o_l = idx & 63;
    tile[s_l][o_l] = yb[(size_t)s_l * 256 + o_l];
  }
  __syncthreads();
  float* ob = out + ((size_t)(b * 256 + ot * 64)) * 4096 + st * 64;
  #pragma unroll
  for (int i = 0; i < 16; ++i) {
    const int idx = t + 256 * i;
    const int o_l = idx >> 6, s_l = idx & 63;
    const int g = o_l >> 3;
    float v = (tile[s_l][o_l] - sm[g]) * sr[g] * sg[o_l] + sb[o_l];
    v = v > 0.f ? v : 0.f;
    ob[(size_t)o_l * 4096 + s_l] = v;
  }
}

extern "C" void kernel_launch(void* const* d_in, const int* in_sizes, int n_in,
                              void* d_out, int out_size, void* d_ws, size_t ws_size,
                              hipStream_t stream) {
  const float* x = (const float*)d_in[0];       // (4,256,64,64)
  const float* off = (const float*)d_in[1];     // (4,18,64,64)
  const float* w = (const float*)d_in[2];       // (256,256,3,3)
  const float* gamma = (const float*)d_in[3];   // (256)
  const float* beta = (const float*)d_in[4];    // (256)
  float* out = (float*)d_out;

  char* ws = (char*)d_ws;
  float* y = (float*)(ws);                        // 16,777,216 B  [b][s][o] f32
  ushort_t* xt = (ushort_t*)(ws + 16777216);      //  8,388,608 B  [b][h][w][c] bf16
  ushort_t* wb = (ushort_t*)(ws + 25165824);      //  1,179,648 B  [k][o][c] bf16
  float* stats = (float*)(ws + 26345472);         //      1,024 B  [b][g]{sum,ss}

  hipMemsetAsync(stats, 0, 1024, stream);
  k_prep_w<<<256, 256, 0, stream>>>(w, wb);
  k_prep_x<<<1024, 256, 0, stream>>>(x, xt);
  k_gemm<<<256, 256, 0, stream>>>(off, xt, wb, y);
  k_stats<<<32, 256, 0, stream>>>(y, stats);
  k_apply<<<1024, 256, 0, stream>>>(y, stats, gamma, beta, out);
}